// Round 12
// baseline (443.749 us; speedup 1.0000x reference)
//
#include <hip/hip_runtime.h>
#include <hip/hip_bf16.h>
#include <hip/hip_cooperative_groups.h>

namespace cg = cooperative_groups;

#define N_NODES 100000
#define N_EDGES 600000
#define D 128
#define ROWS_PB 32                               // dst rows per tile
#define NTILE (N_NODES / ROWS_PB)                // 3125
#define CAPN 32                                  // per-node bucket capacity (mean deg 6, P(>31)~3e-16)
#define GSTR 132                                 // padded LDS row stride (floats)
#define GRID_B 1024                              // 4 blocks/CU x 256 CUs (co-resident)
#define NTHR (GRID_B * 256)                      // 262144 threads

typedef __attribute__((ext_vector_type(8))) short short8;
typedef __attribute__((ext_vector_type(8))) unsigned short ushort8;
typedef __attribute__((ext_vector_type(4))) float f32x4;
typedef __attribute__((ext_vector_type(2))) int i32x2;
typedef __attribute__((ext_vector_type(2))) float f32x2;

union V8 { short8 s8; ushort8 u8; };

__device__ __forceinline__ unsigned short f2bf(float f) {
    unsigned u = __float_as_uint(f);
    u += 0x7FFF + ((u >> 16) & 1);   // RNE
    return (unsigned short)(u >> 16);
}

// ======== shared device helpers (used by both paths) ========
__device__ __forceinline__ void wfrag_body(int id, const float* Wi,
                                           const float* We,
                                           unsigned short* Wfi,
                                           unsigned short* Wfe) {
    int mat = id >> 11;
    int idx = id & 2047;          // nt<<8 | ks<<6 | lane
    int lane = idx & 63;
    int ks = (idx >> 6) & 3;
    int nt = idx >> 8;
    int n = lane & 15, quad = lane >> 4;
    int row = nt * 16 + n;
    int k0 = ks * 32 + quad * 8;
    const float* W = mat ? We : Wi;
    unsigned short* Wf = mat ? Wfe : Wfi;
    #pragma unroll
    for (int j = 0; j < 8; ++j)
        Wf[idx * 8 + j] = f2bf(W[row * D + k0 + j]);
}

// Fused tile body (round-10 verified): gather via register-resident bucket
// metadata + __shfl + 2-deep row prefetch; then dual MFMA + leaky + store.
__device__ __forceinline__ void fused_tile(
    int d0, int t, float* g,
    const float* __restrict__ src_x, const float* __restrict__ dst_x,
    const i32x2* __restrict__ bkt, const unsigned* __restrict__ cur,
    const unsigned short* __restrict__ Wfi,
    const unsigned short* __restrict__ Wfe,
    float* __restrict__ out) {
    int lane = t & 63, w = t >> 6;
    int quad = lane >> 4, nl = lane & 15;
    int qid = t >> 4;
    int lbase = (lane >> 4) << 4;

    #pragma unroll
    for (int half = 0; half < 2; ++half) {
        int r = 2 * qid + half;
        int node = d0 + r;
        int cn = (int)cur[node];
        if (cn > CAPN) cn = CAPN;
        const i32x2* bp = bkt + (size_t)node * CAPN;
        i32x2 mA = __builtin_nontemporal_load(&bp[nl]);
        i32x2 mB = __builtin_nontemporal_load(&bp[nl + 16]);
        float4 a = {0.f, 0.f, 0.f, 0.f}, c = {0.f, 0.f, 0.f, 0.f};
        if (cn > 0) {
            int s0 = __shfl(mA[0], lbase);
            float w0 = __int_as_float(__shfl(mA[1], lbase));
            int i1 = (cn > 1) ? 1 : 0;
            int s1 = __shfl(mA[0], lbase | i1);
            float w1 = __int_as_float(__shfl(mA[1], lbase | i1));
            const float* p0 = src_x + (size_t)s0 * D + nl * 8;
            float4 A0 = *(const float4*)p0, B0 = *(const float4*)(p0 + 4);
            const float* p1 = src_x + (size_t)s1 * D + nl * 8;
            float4 A1 = *(const float4*)p1, B1 = *(const float4*)(p1 + 4);
            for (int e = 0; e < cn; ++e) {
                int k = e + 2; if (k > cn - 1) k = cn - 1;
                int srcl = lbase | (k & 15);
                int sk = __shfl(k < 16 ? mA[0] : mB[0], srcl);
                float wk = __int_as_float(__shfl(k < 16 ? mA[1] : mB[1], srcl));
                const float* pk = src_x + (size_t)sk * D + nl * 8;
                float4 A2 = *(const float4*)pk, B2 = *(const float4*)(pk + 4);
                a.x += w0 * A0.x; a.y += w0 * A0.y;
                a.z += w0 * A0.z; a.w += w0 * A0.w;
                c.x += w0 * B0.x; c.y += w0 * B0.y;
                c.z += w0 * B0.z; c.w += w0 * B0.w;
                A0 = A1; B0 = B1; w0 = w1;
                A1 = A2; B1 = B2; w1 = wk;
            }
        }
        float* gp = &g[r * GSTR + nl * 8];
        *(float4*)gp = a;
        *(float4*)(gp + 4) = c;
    }
    __syncthreads();

    const short8* Wiv = (const short8*)Wfi;
    const short8* Wev = (const short8*)Wfe;
    short8 Bi[2][4], Be[2][4];
    #pragma unroll
    for (int ntl = 0; ntl < 2; ++ntl)
        #pragma unroll
        for (int ks = 0; ks < 4; ++ks) {
            Bi[ntl][ks] = Wiv[((2 * w + ntl) * 4 + ks) * 64 + lane];
            Be[ntl][ks] = Wev[((2 * w + ntl) * 4 + ks) * 64 + lane];
        }

    #pragma unroll
    for (int tl = 0; tl < 2; ++tl) {
        int r = tl * 16 + nl;
        const float* xr = dst_x + (size_t)(d0 + r) * D + quad * 8;
        const float* gr = &g[r * GSTR + quad * 8];
        f32x4 acc[2];
        acc[0] = (f32x4){0.f, 0.f, 0.f, 0.f};
        acc[1] = (f32x4){0.f, 0.f, 0.f, 0.f};
        #pragma unroll
        for (int ks = 0; ks < 4; ++ks) {
            float4 f0 = *(const float4*)(xr + ks * 32);
            float4 f1 = *(const float4*)(xr + ks * 32 + 4);
            float4 g0 = *(const float4*)(gr + ks * 32);
            float4 g1 = *(const float4*)(gr + ks * 32 + 4);
            V8 a1v, a2v;
            a1v.u8[0] = f2bf(f0.x + g0.x); a2v.u8[0] = f2bf(f0.x * g0.x);
            a1v.u8[1] = f2bf(f0.y + g0.y); a2v.u8[1] = f2bf(f0.y * g0.y);
            a1v.u8[2] = f2bf(f0.z + g0.z); a2v.u8[2] = f2bf(f0.z * g0.z);
            a1v.u8[3] = f2bf(f0.w + g0.w); a2v.u8[3] = f2bf(f0.w * g0.w);
            a1v.u8[4] = f2bf(f1.x + g1.x); a2v.u8[4] = f2bf(f1.x * g1.x);
            a1v.u8[5] = f2bf(f1.y + g1.y); a2v.u8[5] = f2bf(f1.y * g1.y);
            a1v.u8[6] = f2bf(f1.z + g1.z); a2v.u8[6] = f2bf(f1.z * g1.z);
            a1v.u8[7] = f2bf(f1.w + g1.w); a2v.u8[7] = f2bf(f1.w * g1.w);
            acc[0] = __builtin_amdgcn_mfma_f32_16x16x32_bf16(a1v.s8, Bi[0][ks], acc[0], 0, 0, 0);
            acc[1] = __builtin_amdgcn_mfma_f32_16x16x32_bf16(a1v.s8, Bi[1][ks], acc[1], 0, 0, 0);
            acc[0] = __builtin_amdgcn_mfma_f32_16x16x32_bf16(a2v.s8, Be[0][ks], acc[0], 0, 0, 0);
            acc[1] = __builtin_amdgcn_mfma_f32_16x16x32_bf16(a2v.s8, Be[1][ks], acc[1], 0, 0, 0);
        }
        #pragma unroll
        for (int ntl = 0; ntl < 2; ++ntl)
            #pragma unroll
            for (int rr = 0; rr < 4; ++rr) {
                float v = acc[ntl][rr];
                v = v > 0.f ? v : 0.01f * v;
                out[(size_t)(d0 + tl * 16 + quad * 4 + rr) * D
                    + (2 * w + ntl) * 16 + nl] = v;
            }
    }
}

// ======== path 1: single cooperative kernel ========
__global__ __launch_bounds__(256, 4) void mono_kernel(
    const float* __restrict__ src_x,
    const float* __restrict__ dst_x,
    const int* __restrict__ src_idx,
    const int* __restrict__ dst_idx,
    const float* __restrict__ ew,
    const float* __restrict__ Wi,
    const float* __restrict__ We,
    unsigned short* __restrict__ Wfi,
    unsigned short* __restrict__ Wfe,
    unsigned* __restrict__ cur,
    i32x2* __restrict__ bkt,
    float* __restrict__ out) {
    __shared__ float g[ROWS_PB * GSTR];   // 16.9 KB

    cg::grid_group grid = cg::this_grid();
    int t = threadIdx.x;
    int gid = blockIdx.x * 256 + t;

    // phase A: cursor clear + W fragments
    if (gid < N_NODES) cur[gid] = 0u;
    if (gid < 4096) wfrag_body(gid, Wi, We, Wfi, Wfe);
    grid.sync();

    // phase B: bucket scatter (grid-strided)
    for (int e = gid; e < N_EDGES; e += NTHR) {
        int s = src_idx[e];
        int d = dst_idx[e];
        float wv = ew[e];
        unsigned pos = atomicAdd(&cur[d], 1u);
        if (pos < CAPN) {
            i32x2 m = {s, __float_as_int(wv)};
            bkt[(size_t)d * CAPN + pos] = m;
        }
    }
    grid.sync();

    // phase C: fused tiles
    for (int tile = blockIdx.x; tile < NTILE; tile += GRID_B) {
        fused_tile(tile * ROWS_PB, t, g, src_x, dst_x, bkt, cur, Wfi, Wfe, out);
        __syncthreads();   // protect g before next tile's gather
    }
}

// ======== path 2: round-10 verified 3-dispatch fallback ========
__global__ void wfrag_kernel(const float* __restrict__ Wi,
                             const float* __restrict__ We,
                             unsigned short* __restrict__ Wfi,
                             unsigned short* __restrict__ Wfe,
                             unsigned* __restrict__ cur) {
    int id = blockIdx.x * blockDim.x + threadIdx.x;   // 0..16383
    for (int j = id; j < N_NODES; j += 16384) cur[j] = 0u;
    if (id >= 4096) return;
    wfrag_body(id, Wi, We, Wfi, Wfe);
}

__global__ void scatter_kernel(const i32x2* __restrict__ src2,
                               const i32x2* __restrict__ dst2,
                               const f32x2* __restrict__ ew2,
                               unsigned* __restrict__ cur,
                               i32x2* __restrict__ bkt) {
    int i = blockIdx.x * blockDim.x + threadIdx.x;
    if (i < N_EDGES / 2) {
        i32x2 s = __builtin_nontemporal_load(&src2[i]);
        i32x2 d = __builtin_nontemporal_load(&dst2[i]);
        f32x2 wv = __builtin_nontemporal_load(&ew2[i]);
        unsigned p0 = atomicAdd(&cur[d[0]], 1u);
        unsigned p1 = atomicAdd(&cur[d[1]], 1u);
        if (p0 < CAPN) {
            i32x2 m = {s[0], __float_as_int(wv[0])};
            __builtin_nontemporal_store(m, &bkt[(size_t)d[0] * CAPN + p0]);
        }
        if (p1 < CAPN) {
            i32x2 m = {s[1], __float_as_int(wv[1])};
            __builtin_nontemporal_store(m, &bkt[(size_t)d[1] * CAPN + p1]);
        }
    }
}

__global__ __launch_bounds__(256, 4) void fused_kernel(
    const float* __restrict__ src_x,
    const float* __restrict__ dst_x,
    const i32x2* __restrict__ bkt,
    const unsigned* __restrict__ cur,
    const unsigned short* __restrict__ Wfi,
    const unsigned short* __restrict__ Wfe,
    float* __restrict__ out) {
    __shared__ float g[ROWS_PB * GSTR];
    fused_tile(blockIdx.x * ROWS_PB, threadIdx.x, g,
               src_x, dst_x, bkt, cur, Wfi, Wfe, out);
}

extern "C" void kernel_launch(void* const* d_in, const int* in_sizes, int n_in,
                              void* d_out, int out_size, void* d_ws, size_t ws_size,
                              hipStream_t stream) {
    const float* src_x = (const float*)d_in[0];
    const float* dst_x = (const float*)d_in[1];
    const int*   eidx  = (const int*)d_in[2];     // [2, E] flat: src then dst
    const float* ew    = (const float*)d_in[3];   // [E, 1]
    const float* Wi    = (const float*)d_in[4];   // [D, D]
    const float* We    = (const float*)d_in[5];   // [D, D]
    float* out = (float*)d_out;

    // ws layout
    char* wsb = (char*)d_ws;
    unsigned short* Wfi = (unsigned short*)(wsb);            // 32768 B
    unsigned short* Wfe = (unsigned short*)(wsb + 32768);    // 32768 B
    unsigned* cur = (unsigned*)(wsb + 65536);                // 400000 B
    i32x2* bkt = (i32x2*)(wsb + 65536 + 400000);             // 25.6 MB

    const int* src_idx = eidx;
    const int* dst_idx = eidx + N_EDGES;

    void* args[] = {
        (void*)&src_x, (void*)&dst_x, (void*)&src_idx, (void*)&dst_idx,
        (void*)&ew, (void*)&Wi, (void*)&We,
        (void*)&Wfi, (void*)&Wfe, (void*)&cur, (void*)&bkt, (void*)&out
    };
    hipError_t err = hipLaunchCooperativeKernel(
        (const void*)mono_kernel, dim3(GRID_B), dim3(256), args, 0, stream);
    if (err != hipSuccess) {
        // fallback: round-10 verified 3-dispatch path (246 us)
        wfrag_kernel<<<64, 256, 0, stream>>>(Wi, We, Wfi, Wfe, cur);
        scatter_kernel<<<(N_EDGES / 2 + 255) / 256, 256, 0, stream>>>(
            (const i32x2*)src_idx, (const i32x2*)dst_idx, (const f32x2*)ew,
            cur, bkt);
        fused_kernel<<<NTILE, 256, 0, stream>>>(
            src_x, dst_x, bkt, cur, Wfi, Wfe, out);
    }
}

// Round 13
// 258.277 us; speedup vs baseline: 1.7181x; 1.7181x over previous
//
#include <hip/hip_runtime.h>
#include <hip/hip_bf16.h>

#define N_NODES 100000
#define N_EDGES 600000
#define D 128
#define ROWS_PB 32                               // dst rows per fused block
#define NBLK_F (N_NODES / ROWS_PB)               // 3125
#define CAPN 32                                  // per-node bucket capacity (mean deg 6, P(>31)~3e-16)
#define GSTR 132                                 // padded LDS row stride (floats)

typedef __attribute__((ext_vector_type(8))) short short8;
typedef __attribute__((ext_vector_type(8))) unsigned short ushort8;
typedef __attribute__((ext_vector_type(4))) float f32x4;
typedef __attribute__((ext_vector_type(2))) int i32x2;
typedef __attribute__((ext_vector_type(2))) float f32x2;

union V8 { short8 s8; ushort8 u8; };

__device__ __forceinline__ unsigned short f2bf(float f) {
    unsigned u = __float_as_uint(f);
    u += 0x7FFF + ((u >> 16) & 1);   // RNE
    return (unsigned short)(u >> 16);
}

// ---------------- weight fragments + per-node cursor zeroing ----------------
__global__ void wfrag_kernel(const float* __restrict__ Wi,
                             const float* __restrict__ We,
                             unsigned short* __restrict__ Wfi,
                             unsigned short* __restrict__ Wfe,
                             unsigned* __restrict__ cur) {
    int id = blockIdx.x * blockDim.x + threadIdx.x;   // 0..16383
    for (int j = id; j < N_NODES; j += 16384) cur[j] = 0u;   // fold memset in
    if (id >= 4096) return;
    int mat = id >> 11;
    int idx = id & 2047;          // nt<<8 | ks<<6 | lane
    int lane = idx & 63;
    int ks = (idx >> 6) & 3;
    int nt = idx >> 8;
    int n = lane & 15, quad = lane >> 4;
    int row = nt * 16 + n;
    int k0 = ks * 32 + quad * 8;
    const float* W = mat ? We : Wi;
    unsigned short* Wf = mat ? Wfe : Wfi;
    #pragma unroll
    for (int j = 0; j < 8; ++j)
        Wf[idx * 8 + j] = f2bf(W[row * D + k0 + j]);
}

// ---------------- one-pass per-node bucket scatter ----------------
__global__ void scatter_kernel(const i32x2* __restrict__ src2,
                               const i32x2* __restrict__ dst2,
                               const f32x2* __restrict__ ew2,
                               unsigned* __restrict__ cur,
                               i32x2* __restrict__ bkt) {
    int i = blockIdx.x * blockDim.x + threadIdx.x;
    if (i < N_EDGES / 2) {
        i32x2 s = __builtin_nontemporal_load(&src2[i]);
        i32x2 d = __builtin_nontemporal_load(&dst2[i]);
        f32x2 wv = __builtin_nontemporal_load(&ew2[i]);
        unsigned p0 = atomicAdd(&cur[d[0]], 1u);
        unsigned p1 = atomicAdd(&cur[d[1]], 1u);
        if (p0 < CAPN) {
            i32x2 m = {s[0], __float_as_int(wv[0])};
            __builtin_nontemporal_store(m, &bkt[(size_t)d[0] * CAPN + p0]);
        }
        if (p1 < CAPN) {
            i32x2 m = {s[1], __float_as_int(wv[1])};
            __builtin_nontemporal_store(m, &bkt[(size_t)d[1] * CAPN + p1]);
        }
    }
}

// ---------------- fused gather-sum + dual GEMM + leaky ----------------
// out = leaky( (dst_x + g) @ Wi^T + (dst_x .* g) @ We^T ),
// g[d] = sum_{e: dst=d} ew_e * src_x[src_e]  (exact f32).
// Gather: quad owns 2 nodes (rows 2q, 2q+1), chains INTERLEAVED in one
// loop. Each chain: register-resident bucket metadata (one i32x2/lane/half,
// slot k via __shfl from lane lbase|(k&15); k quad-uniform, source in own
// quad) + 2-deep row prefetch -> ~4 row loads in flight/lane, zero
// metadata loads on the critical path.
// launch_bounds (256,4): budget 128 VGPR >> ~85 live -> no compression.
// History: (256,6)+dual-chain spilled (r7, 40 VGPR forced); reg-metadata
// single-chain at (256,4) = 98us, VGPR 44, no spill (r10). This combines
// the two proven-safe pieces.
// NOTE (r12): total-time residue ~133us is HARNESS overhead (out memset +
// restore dispatches), not scatter; scatter+wfrag+gaps ~15us. This kernel
// is the only controllable lever (98us vs ~37us BW floor).
__global__ __launch_bounds__(256, 4) void fused_kernel(
    const float* __restrict__ src_x,
    const float* __restrict__ dst_x,
    const i32x2* __restrict__ bkt,
    const unsigned* __restrict__ cur,
    const unsigned short* __restrict__ Wfi,
    const unsigned short* __restrict__ Wfe,
    float* __restrict__ out) {
    __shared__ float g[ROWS_PB * GSTR];   // 32 x 132 f32 = 16.9 KB

    int t = threadIdx.x, lane = t & 63, w = t >> 6;
    int quad = lane >> 4, nl = lane & 15;
    int qid = t >> 4;                      // 0..15
    int lbase = (lane >> 4) << 4;          // first lane of this quad

    int b = blockIdx.x, d0 = b * ROWS_PB;

    // ---- gather: dual interleaved chains (rows 2*qid, 2*qid+1) ----
    int r0 = 2 * qid, r1 = r0 + 1;
    uint2 cn2 = *(const uint2*)&cur[d0 + r0];   // consecutive, 8B-aligned
    int cnX = (int)cn2.x; if (cnX > CAPN) cnX = CAPN;
    int cnY = (int)cn2.y; if (cnY > CAPN) cnY = CAPN;
    const i32x2* bpX = bkt + (size_t)(d0 + r0) * CAPN;
    const i32x2* bpY = bkt + (size_t)(d0 + r1) * CAPN;

    // lane-distributed metadata for both nodes
    i32x2 mAX = __builtin_nontemporal_load(&bpX[nl]);
    i32x2 mBX = __builtin_nontemporal_load(&bpX[nl + 16]);
    i32x2 mAY = __builtin_nontemporal_load(&bpY[nl]);
    i32x2 mBY = __builtin_nontemporal_load(&bpY[nl + 16]);

    float4 aX = {0.f,0.f,0.f,0.f}, cX = {0.f,0.f,0.f,0.f};
    float4 aY = {0.f,0.f,0.f,0.f}, cY = {0.f,0.f,0.f,0.f};

    float4 AX0 = {0,0,0,0}, BX0 = {0,0,0,0}, AX1 = {0,0,0,0}, BX1 = {0,0,0,0};
    float4 AY0 = {0,0,0,0}, BY0 = {0,0,0,0}, AY1 = {0,0,0,0}, BY1 = {0,0,0,0};
    float wX0 = 0.f, wX1 = 0.f, wY0 = 0.f, wY1 = 0.f;

    if (cnX > 0) {
        int s0 = __shfl(mAX[0], lbase);
        wX0 = __int_as_float(__shfl(mAX[1], lbase));
        int i1 = (cnX > 1) ? 1 : 0;
        int s1 = __shfl(mAX[0], lbase | i1);
        wX1 = __int_as_float(__shfl(mAX[1], lbase | i1));
        const float* p0 = src_x + (size_t)s0 * D + nl * 8;
        AX0 = *(const float4*)p0; BX0 = *(const float4*)(p0 + 4);
        const float* p1 = src_x + (size_t)s1 * D + nl * 8;
        AX1 = *(const float4*)p1; BX1 = *(const float4*)(p1 + 4);
    }
    if (cnY > 0) {
        int s0 = __shfl(mAY[0], lbase);
        wY0 = __int_as_float(__shfl(mAY[1], lbase));
        int i1 = (cnY > 1) ? 1 : 0;
        int s1 = __shfl(mAY[0], lbase | i1);
        wY1 = __int_as_float(__shfl(mAY[1], lbase | i1));
        const float* p0 = src_x + (size_t)s0 * D + nl * 8;
        AY0 = *(const float4*)p0; BY0 = *(const float4*)(p0 + 4);
        const float* p1 = src_x + (size_t)s1 * D + nl * 8;
        AY1 = *(const float4*)p1; BY1 = *(const float4*)(p1 + 4);
    }

    int maxcn = cnX > cnY ? cnX : cnY;
    for (int e = 0; e < maxcn; ++e) {
        if (e < cnX) {               // quad-uniform branch
            int k = e + 2; if (k > cnX - 1) k = cnX - 1;
            int srcl = lbase | (k & 15);
            int sk = __shfl(k < 16 ? mAX[0] : mBX[0], srcl);
            float wk = __int_as_float(__shfl(k < 16 ? mAX[1] : mBX[1], srcl));
            const float* pk = src_x + (size_t)sk * D + nl * 8;
            float4 A2 = *(const float4*)pk, B2 = *(const float4*)(pk + 4);
            aX.x += wX0 * AX0.x; aX.y += wX0 * AX0.y;
            aX.z += wX0 * AX0.z; aX.w += wX0 * AX0.w;
            cX.x += wX0 * BX0.x; cX.y += wX0 * BX0.y;
            cX.z += wX0 * BX0.z; cX.w += wX0 * BX0.w;
            AX0 = AX1; BX0 = BX1; wX0 = wX1;
            AX1 = A2;  BX1 = B2;  wX1 = wk;
        }
        if (e < cnY) {
            int k = e + 2; if (k > cnY - 1) k = cnY - 1;
            int srcl = lbase | (k & 15);
            int sk = __shfl(k < 16 ? mAY[0] : mBY[0], srcl);
            float wk = __int_as_float(__shfl(k < 16 ? mAY[1] : mBY[1], srcl));
            const float* pk = src_x + (size_t)sk * D + nl * 8;
            float4 A2 = *(const float4*)pk, B2 = *(const float4*)(pk + 4);
            aY.x += wY0 * AY0.x; aY.y += wY0 * AY0.y;
            aY.z += wY0 * AY0.z; aY.w += wY0 * AY0.w;
            cY.x += wY0 * BY0.x; cY.y += wY0 * BY0.y;
            cY.z += wY0 * BY0.z; cY.w += wY0 * BY0.w;
            AY0 = AY1; BY0 = BY1; wY0 = wY1;
            AY1 = A2;  BY1 = B2;  wY1 = wk;
        }
    }

    {   // plain stores: quad owns both rows
        float* gp0 = &g[r0 * GSTR + nl * 8];
        *(float4*)gp0 = aX; *(float4*)(gp0 + 4) = cX;
        float* gp1 = &g[r1 * GSTR + nl * 8];
        *(float4*)gp1 = aY; *(float4*)(gp1 + 4) = cY;
    }
    __syncthreads();

    // ---- MFMA phase: W fragments (compiler sinks loads here) ----
    const short8* Wiv = (const short8*)Wfi;
    const short8* Wev = (const short8*)Wfe;
    short8 Bi[2][4], Be[2][4];
    #pragma unroll
    for (int ntl = 0; ntl < 2; ++ntl)
        #pragma unroll
        for (int ks = 0; ks < 4; ++ks) {
            Bi[ntl][ks] = Wiv[((2 * w + ntl) * 4 + ks) * 64 + lane];
            Be[ntl][ks] = Wev[((2 * w + ntl) * 4 + ks) * 64 + lane];
        }

    #pragma unroll
    for (int tl = 0; tl < 2; ++tl) {
        int r = tl * 16 + nl;                        // local row 0..31
        const float* xr = dst_x + (size_t)(d0 + r) * D + quad * 8;
        const float* gr = &g[r * GSTR + quad * 8];
        f32x4 acc[2];
        acc[0] = (f32x4){0.f, 0.f, 0.f, 0.f};
        acc[1] = (f32x4){0.f, 0.f, 0.f, 0.f};
        #pragma unroll
        for (int ks = 0; ks < 4; ++ks) {
            float4 f0 = *(const float4*)(xr + ks * 32);
            float4 f1 = *(const float4*)(xr + ks * 32 + 4);
            float4 g0 = *(const float4*)(gr + ks * 32);
            float4 g1 = *(const float4*)(gr + ks * 32 + 4);
            V8 a1v, a2v;
            a1v.u8[0] = f2bf(f0.x + g0.x); a2v.u8[0] = f2bf(f0.x * g0.x);
            a1v.u8[1] = f2bf(f0.y + g0.y); a2v.u8[1] = f2bf(f0.y * g0.y);
            a1v.u8[2] = f2bf(f0.z + g0.z); a2v.u8[2] = f2bf(f0.z * g0.z);
            a1v.u8[3] = f2bf(f0.w + g0.w); a2v.u8[3] = f2bf(f0.w * g0.w);
            a1v.u8[4] = f2bf(f1.x + g1.x); a2v.u8[4] = f2bf(f1.x * g1.x);
            a1v.u8[5] = f2bf(f1.y + g1.y); a2v.u8[5] = f2bf(f1.y * g1.y);
            a1v.u8[6] = f2bf(f1.z + g1.z); a2v.u8[6] = f2bf(f1.z * g1.z);
            a1v.u8[7] = f2bf(f1.w + g1.w); a2v.u8[7] = f2bf(f1.w * g1.w);
            acc[0] = __builtin_amdgcn_mfma_f32_16x16x32_bf16(a1v.s8, Bi[0][ks], acc[0], 0, 0, 0);
            acc[1] = __builtin_amdgcn_mfma_f32_16x16x32_bf16(a1v.s8, Bi[1][ks], acc[1], 0, 0, 0);
            acc[0] = __builtin_amdgcn_mfma_f32_16x16x32_bf16(a2v.s8, Be[0][ks], acc[0], 0, 0, 0);
            acc[1] = __builtin_amdgcn_mfma_f32_16x16x32_bf16(a2v.s8, Be[1][ks], acc[1], 0, 0, 0);
        }
        // store with fused leaky; plain stores (NT cost +15MB WRITE in r8)
        #pragma unroll
        for (int ntl = 0; ntl < 2; ++ntl)
            #pragma unroll
            for (int rr = 0; rr < 4; ++rr) {
                float v = acc[ntl][rr];
                v = v > 0.f ? v : 0.01f * v;
                out[(size_t)(d0 + tl * 16 + quad * 4 + rr) * D
                    + (2 * w + ntl) * 16 + nl] = v;
            }
    }
}

extern "C" void kernel_launch(void* const* d_in, const int* in_sizes, int n_in,
                              void* d_out, int out_size, void* d_ws, size_t ws_size,
                              hipStream_t stream) {
    const float* src_x = (const float*)d_in[0];
    const float* dst_x = (const float*)d_in[1];
    const int*   eidx  = (const int*)d_in[2];     // [2, E] flat: src then dst
    const float* ew    = (const float*)d_in[3];   // [E, 1]
    const float* Wi    = (const float*)d_in[4];   // [D, D]
    const float* We    = (const float*)d_in[5];   // [D, D]
    float* out = (float*)d_out;

    // ws layout
    char* wsb = (char*)d_ws;
    unsigned short* Wfi = (unsigned short*)(wsb);            // 32768 B
    unsigned short* Wfe = (unsigned short*)(wsb + 32768);    // 32768 B
    unsigned* cur = (unsigned*)(wsb + 65536);                // 400000 B
    i32x2* bkt = (i32x2*)(wsb + 65536 + 400000);             // 25.6 MB

    const int* src_idx = eidx;
    const int* dst_idx = eidx + N_EDGES;

    wfrag_kernel<<<64, 256, 0, stream>>>(Wi, We, Wfi, Wfe, cur);

    scatter_kernel<<<(N_EDGES / 2 + 255) / 256, 256, 0, stream>>>(
        (const i32x2*)src_idx, (const i32x2*)dst_idx, (const f32x2*)ew,
        cur, bkt);

    fused_kernel<<<NBLK_F, 256, 0, stream>>>(
        src_x, dst_x, bkt, cur, Wfi, Wfe, out);
}